// Round 1
// 1263.770 us; speedup vs baseline: 1.1277x; 1.1277x over previous
//
#include <hip/hip_runtime.h>
#include <math.h>

typedef unsigned short u16;
typedef __bf16 bf16x8 __attribute__((ext_vector_type(8)));
typedef float floatx4 __attribute__((ext_vector_type(4)));
typedef unsigned int u32x4 __attribute__((ext_vector_type(4)));

#define DIM 2048
#define NEXP 32
#define TOPK 4
#define INTER 1024
#define SINTER 2048
#define NTOK 2048
#define MAXROWS 12288   // <=96 tiles * 128 padded rows
#define MAXTILES 96

__device__ __forceinline__ u16 f2bf(float f) {
  unsigned int u = __float_as_uint(f);
  u += 0x7FFF + ((u >> 16) & 1);   // RNE
  return (u16)(u >> 16);
}
__device__ __forceinline__ float bf2f(u16 s) { return __uint_as_float(((unsigned int)s) << 16); }

// ---------------- cast x (fp32) -> xb (bf16, RNE) ----------------
__global__ __launch_bounds__(256) void cast_x_kernel(const float* __restrict__ x,
                                                     u16* __restrict__ xb) {
  size_t i = ((size_t)blockIdx.x * blockDim.x + threadIdx.x) * 4;
  float4 v = *(const float4*)(x + i);
  unsigned int p0 = (unsigned int)f2bf(v.x) | ((unsigned int)f2bf(v.y) << 16);
  unsigned int p1 = (unsigned int)f2bf(v.z) | ((unsigned int)f2bf(v.w) << 16);
  *(uint2*)(xb + i) = make_uint2(p0, p1);
}

// ---------------- gate: logits, softmax, top-4, counts (one wave / token) -----
__global__ __launch_bounds__(256) void gate_kernel(const float* __restrict__ x,
                                                   const float* __restrict__ gw,
                                                   int* __restrict__ topi,
                                                   float* __restrict__ topw,
                                                   int* __restrict__ counts) {
  int wave = threadIdx.x >> 6, lane = threadIdx.x & 63;
  int t = blockIdx.x * 4 + wave;
  int e = lane & 31;
  int hh = lane >> 5;
  const float* xr = x + (size_t)t * DIM + hh * (DIM / 2);
  const float* gr = gw + (size_t)e * DIM + hh * (DIM / 2);
  float acc = 0.f;
  for (int d = 0; d < DIM / 2; d += 4) {
    float4 xv = *(const float4*)(xr + d);
    float4 gv = *(const float4*)(gr + d);
    acc += xv.x * gv.x + xv.y * gv.y + xv.z * gv.z + xv.w * gv.w;
  }
  acc += __shfl_down(acc, 32);     // lanes 0..31 hold full logit for expert e
  float lg = acc;
  float mx = lg;
  for (int m = 16; m; m >>= 1) mx = fmaxf(mx, __shfl_xor(mx, m));
  float ex = __expf(lg - mx);
  float sum = ex;
  for (int m = 16; m; m >>= 1) sum += __shfl_xor(sum, m);
  float s = ex / sum;
  if (lane >= 32) s = -1.f;        // exclude upper half from top-k
  int idx = e;
  for (int k = 0; k < TOPK; ++k) {
    float bv = s; int bi = idx;
    for (int m = 16; m; m >>= 1) {
      float ov = __shfl_xor(bv, m);
      int oi = __shfl_xor(bi, m);
      if (ov > bv || (ov == bv && oi < bi)) { bv = ov; bi = oi; }  // jax: lowest idx on tie
    }
    if (lane == 0) {
      topi[t * TOPK + k] = bi;
      topw[t * TOPK + k] = bv;     // raw softmax score (route_scale = 1)
      atomicAdd(&counts[bi], 1);
    }
    if (lane == bi) s = -1e30f;
  }
}

// ---------------- zero the atomic counters ----------------
__global__ void zero_ctrl(int* __restrict__ c) { c[threadIdx.x] = 0; }

// ---------------- plan: padded offsets + tile table + map init ----------------
__global__ void plan_kernel(const int* __restrict__ counts, int* __restrict__ poff,
                            int* __restrict__ ntiles, int* __restrict__ tileE,
                            int* __restrict__ tileR, int* __restrict__ mapT,
                            float* __restrict__ mapW) {
  if (threadIdx.x == 0) {
    int off = 0, tt = 0;
    for (int e = 0; e < NEXP; ++e) {
      poff[e] = off;
      int c = counts[e];
      int nt = (c + 127) >> 7;
      for (int i = 0; i < nt; ++i) { tileE[tt] = e; tileR[tt] = off + (i << 7); ++tt; }
      off += nt << 7;
    }
    ntiles[0] = tt;
  }
  for (int i = threadIdx.x; i < MAXROWS; i += blockDim.x) { mapT[i] = 0; mapW[i] = 0.f; }
}

// ---------------- scatter tokens into expert buckets ----------------
__global__ void scatter_kernel(const int* __restrict__ topi, const float* __restrict__ topw,
                               const int* __restrict__ poff, int* __restrict__ fill,
                               int* __restrict__ mapT, float* __restrict__ mapW) {
  int i = blockIdx.x * blockDim.x + threadIdx.x;
  if (i >= NTOK * TOPK) return;
  int e = topi[i];
  int pos = poff[e] + atomicAdd(&fill[e], 1);
  mapT[pos] = i >> 2;
  mapW[pos] = topw[i];
}

// ------- GEMM C = A(bf16) * B(fp32)^T, 128x128 tile, BK=64, m97 structure -----
// A staged async bf16 (16 KB), B staged async fp32 (32 KB), B converted to bf16
// at fragment load (1 v_perm per pair).
// LDS XOR-swizzle (rule #21: linear global_load_lds dest + inverse-swizzled
// global SOURCE + same swizzle on READ): slot(row, chunk) holds global chunk
// (chunk ^ (row&7)); kills the 16-way bank conflict of row-major tiles at
// 128B/256B row stride (SQ_LDS_BANK_CONFLICT 4.3e7 -> ~0).
// EPI: 0 = store bf16; 1 = silu(aux)*acc bf16; 2 = atomicAdd(acc*wgt[row])
// into fp32 y at mapOut row; 3 = fp32 store.
template <int EPI>
__global__ __launch_bounds__(256) void gemm_bt(
    const u16* __restrict__ A, const float* __restrict__ B,
    int lda, int ldb, int K, long long strideE,
    const int* __restrict__ tileE, const int* __restrict__ tileR, const int* __restrict__ pNT,
    const int* __restrict__ mapA, const int* __restrict__ mapOut, const float* __restrict__ wgt,
    const u16* __restrict__ aux, void* __restrict__ Cout, int ldc) {
  int mtile = blockIdx.y, ntile = blockIdx.x;
  int e = 0, row0;
  if (tileE) {
    if (mtile >= pNT[0]) return;   // uniform early-exit for unused tiles
    e = tileE[mtile];
    row0 = tileR[mtile];
  } else {
    row0 = mtile << 7;
  }

  __shared__ u16 As[128 * 64];     // 16 KB, row-major 128 x BK=64 bf16 (swizzled)
  __shared__ float Bs[128 * 64];   // 32 KB, row-major 128 x BK=64 fp32 (swizzled)
  __shared__ int rowTok[128];

  int tid = threadIdx.x, wave = tid >> 6, lane = tid & 63;
  if (tid < 128) rowTok[tid] = mapA ? mapA[row0 + tid] : (row0 + tid);
  __syncthreads();

  const float* Be = B + (size_t)e * strideE;

  // A source pre-swizzle: LDS dest slot for lane L is (row = g*8 + (L>>3),
  // chunk = L&7); it must hold global chunk (L&7) ^ (row&7) = (L&7) ^ (L>>3).
  const u16* ga[4];
  int cA = ((lane & 7) ^ (lane >> 3)) * 8;   // u16 offset of swizzled 16B chunk
#pragma unroll
  for (int i = 0; i < 4; ++i) {
    int r = wave * 32 + i * 8 + (lane >> 3);
    ga[i] = A + (size_t)rowTok[r] * lda + cA;
  }

  // B source pre-swizzle: dest slot (row = w*32 + i*4 + (L>>4), chunk = L&15)
  // must hold global chunk (L&15) ^ (row&7) = (L&15) ^ (L>>4) ^ ((i&1)<<2).
  int cB = (lane & 15) ^ (lane >> 4);
  const float* gbE = Be + (size_t)(ntile * 128 + wave * 32 + (lane >> 4)) * ldb + cB * 4;
  const float* gbO = Be + (size_t)(ntile * 128 + wave * 32 + (lane >> 4)) * ldb + (cB ^ 4) * 4;

  floatx4 acc[4][4];
  floatx4 zero = {0.f, 0.f, 0.f, 0.f};
#pragma unroll
  for (int i = 0; i < 4; ++i)
#pragma unroll
    for (int j = 0; j < 4; ++j) acc[i][j] = zero;

  int wm = wave & 1, wn = wave >> 1;
  int quad = lane >> 4, l15 = lane & 15;
  int sA = (l15 & 7) << 3;   // read-side XOR, u16 units (A: 16B chunk = 8 u16)
  int sB = (l15 & 7) << 2;   // read-side XOR, float units (B: 16B chunk = 4 floats)

  for (int k0 = 0; k0 < K; k0 += 64) {
#pragma unroll
    for (int i = 0; i < 4; ++i)   // A: 4 chunks/wave, 8 rows each (128 B rows)
      __builtin_amdgcn_global_load_lds((const void*)(ga[i] + k0),
                                       (void*)(As + (wave * 4 + i) * 512 + lane * 8), 16, 0, 0);
#pragma unroll
    for (int i = 0; i < 8; ++i) {  // B: 8 chunks/wave, 4 rows each (256 B rows)
      const float* src = ((i & 1) ? gbO : gbE) + k0 + (size_t)i * 4 * ldb;
      __builtin_amdgcn_global_load_lds((const void*)src,
                                       (void*)(Bs + (wave * 32 + i * 4) * 64 + lane * 4), 16, 0, 0);
    }
    __syncthreads();
#pragma unroll
    for (int kk = 0; kk < 64; kk += 32) {
      bf16x8 af[4], bfr[4];
#pragma unroll
      for (int mt = 0; mt < 4; ++mt)
        af[mt] = *(const bf16x8*)(const void*)(As + (wm * 64 + mt * 16 + l15) * 64 +
                                               ((kk + quad * 8) ^ sA));
#pragma unroll
      for (int nt = 0; nt < 4; ++nt) {
        const float* bb = Bs + (wn * 64 + nt * 16 + l15) * 64;
        float4 f0 = *(const float4*)(bb + ((kk + quad * 8) ^ sB));
        float4 f1 = *(const float4*)(bb + (((kk + quad * 8) + 4) ^ sB));
        u32x4 rr;
        rr.x = __builtin_amdgcn_perm(__float_as_uint(f0.y), __float_as_uint(f0.x), 0x07060302u);
        rr.y = __builtin_amdgcn_perm(__float_as_uint(f0.w), __float_as_uint(f0.z), 0x07060302u);
        rr.z = __builtin_amdgcn_perm(__float_as_uint(f1.y), __float_as_uint(f1.x), 0x07060302u);
        rr.w = __builtin_amdgcn_perm(__float_as_uint(f1.w), __float_as_uint(f1.z), 0x07060302u);
        bfr[nt] = __builtin_bit_cast(bf16x8, rr);
      }
#pragma unroll
      for (int mt = 0; mt < 4; ++mt)
#pragma unroll
        for (int nt = 0; nt < 4; ++nt)
          acc[mt][nt] = __builtin_amdgcn_mfma_f32_16x16x32_bf16(af[mt], bfr[nt], acc[mt][nt], 0, 0, 0);
    }
    __syncthreads();
  }

  // epilogue — C/D layout: col = lane&15, row = (lane>>4)*4 + reg  [m89/m91]
#pragma unroll
  for (int mt = 0; mt < 4; ++mt) {
#pragma unroll
    for (int r = 0; r < 4; ++r) {
      int mloc = wm * 64 + mt * 16 + quad * 4 + r;
      int grow = row0 + mloc;
#pragma unroll
      for (int nt = 0; nt < 4; ++nt) {
        int n = ntile * 128 + wn * 64 + nt * 16 + l15;
        float v = acc[mt][nt][r];
        if (EPI == 0) {
          ((u16*)Cout)[(size_t)grow * ldc + n] = f2bf(v);
        } else if (EPI == 1) {
          float uu = bf2f(aux[(size_t)grow * ldc + n]);
          float sl = uu / (1.f + __expf(-uu));
          ((u16*)Cout)[(size_t)grow * ldc + n] = f2bf(sl * v);
        } else if (EPI == 3) {
          ((float*)Cout)[(size_t)grow * ldc + n] = v;
        } else {
          int tok = mapOut[grow];
          float w = wgt[grow];
          if (w != 0.f) atomicAdd(((float*)Cout) + (size_t)tok * ldc + n, v * w);
        }
      }
    }
  }
}

extern "C" void kernel_launch(void* const* d_in, const int* in_sizes, int n_in,
                              void* d_out, int out_size, void* d_ws, size_t ws_size,
                              hipStream_t stream) {
  const float* x   = (const float*)d_in[0];
  const float* gw  = (const float*)d_in[1];
  const float* w1  = (const float*)d_in[2];
  const float* w2  = (const float*)d_in[3];
  const float* w3  = (const float*)d_in[4];
  const float* sw1 = (const float*)d_in[5];
  const float* sw2 = (const float*)d_in[6];
  const float* sw3 = (const float*)d_in[7];
  float* y = (float*)d_out;        // fp32 output; EPI=3 fully overwrites it first

  char* ws = (char*)d_ws;
  size_t off = 0;
  auto alloc = [&](size_t bytes) -> void* {
    void* p = ws + off;
    off += (bytes + 255) & ~(size_t)255;
    return p;
  };
  u16*   xb   = (u16*)  alloc((size_t)NTOK * DIM * 2);
  u16*   u    = (u16*)  alloc((size_t)MAXROWS * INTER * 2);
  u16*   h    = (u16*)  alloc((size_t)MAXROWS * INTER * 2);
  u16*   su   = (u16*)  alloc((size_t)NTOK * SINTER * 2);
  u16*   sh   = (u16*)  alloc((size_t)NTOK * SINTER * 2);
  int*   topi = (int*)  alloc((size_t)NTOK * TOPK * 4);
  float* topw = (float*)alloc((size_t)NTOK * TOPK * 4);
  int*   mapT = (int*)  alloc((size_t)MAXROWS * 4);
  float* mapW = (float*)alloc((size_t)MAXROWS * 4);
  int*   ctrl = (int*)  alloc(4096);
  int* counts = ctrl;        // 32
  int* fill   = ctrl + 32;   // 32
  int* poff   = ctrl + 64;   // 32
  int* ntiles = ctrl + 96;   // 1
  int* tileE  = ctrl + 128;  // 96
  int* tileR  = ctrl + 256;  // 96

  zero_ctrl<<<1, 64, 0, stream>>>(ctrl);
  cast_x_kernel<<<(NTOK * DIM) / 1024, 256, 0, stream>>>(x, xb);
  gate_kernel<<<NTOK / 4, 256, 0, stream>>>(x, gw, topi, topw, counts);
  plan_kernel<<<1, 256, 0, stream>>>(counts, poff, ntiles, tileE, tileR, mapT, mapW);
  scatter_kernel<<<(NTOK * TOPK) / 256, 256, 0, stream>>>(topi, topw, poff, fill, mapT, mapW);

  // routed: u = x@w1^T ; h = silu(u) * (x@w3^T)
  gemm_bt<0><<<dim3(INTER / 128, MAXTILES), 256, 0, stream>>>(
      xb, w1, DIM, DIM, DIM, (long long)INTER * DIM, tileE, tileR, ntiles,
      mapT, nullptr, nullptr, nullptr, u, INTER);
  gemm_bt<1><<<dim3(INTER / 128, MAXTILES), 256, 0, stream>>>(
      xb, w3, DIM, DIM, DIM, (long long)INTER * DIM, tileE, tileR, ntiles,
      mapT, nullptr, nullptr, u, h, INTER);

  // shared: su = x@sw1^T ; sh = silu(su)*(x@sw3^T) ; y = sh@sw2^T (plain store)
  gemm_bt<0><<<dim3(SINTER / 128, NTOK / 128), 256, 0, stream>>>(
      xb, sw1, DIM, DIM, DIM, 0, nullptr, nullptr, nullptr,
      nullptr, nullptr, nullptr, nullptr, su, SINTER);
  gemm_bt<1><<<dim3(SINTER / 128, NTOK / 128), 256, 0, stream>>>(
      xb, sw3, DIM, DIM, DIM, 0, nullptr, nullptr, nullptr,
      nullptr, nullptr, nullptr, su, sh, SINTER);
  gemm_bt<3><<<dim3(DIM / 128, NTOK / 128), 256, 0, stream>>>(
      sh, sw2, SINTER, SINTER, SINTER, 0, nullptr, nullptr, nullptr,
      nullptr, nullptr, nullptr, nullptr, y, DIM);

  // routed down on top of shared result: y += (h@w2^T) * wgt   (fp32 atomics)
  gemm_bt<2><<<dim3(DIM / 128, MAXTILES), 256, 0, stream>>>(
      h, w2, INTER, INTER, INTER, (long long)DIM * INTER, tileE, tileR, ntiles,
      nullptr, mapT, mapW, nullptr, y, DIM);
}